// Round 1
// baseline (579.774 us; speedup 1.0000x reference)
//
#include <hip/hip_runtime.h>

#define BATCH 8
#define CIN   64
#define COUT  64
#define HDIM  128
#define WDIM  128
#define HW    (HDIM * WDIM)
#define KK    9

// ---------------------------------------------------------------------------
// Kernel A: offset-predicting conv (64 -> 18 channels, 3x3, pad 1, stride 1)
// Directly emits absolute sampling positions py/px per (b, tap, pixel).
// Weights are indexed wave-uniformly -> scalar loads; x taps from global (L1).
// ---------------------------------------------------------------------------
__global__ __launch_bounds__(256) void offset_conv_kernel(
    const float* __restrict__ x,
    const float* __restrict__ ow,   // [18][64][3][3]
    const float* __restrict__ ob,   // [18]
    float* __restrict__ py,         // [B][KK][HW]
    float* __restrict__ px)         // [B][KK][HW]
{
    const int tid = threadIdx.x;
    const int b = blockIdx.y;
    const int pixel = blockIdx.x * 256 + tid;
    const int h = pixel >> 7;
    const int w = pixel & 127;

    float acc[18];
#pragma unroll
    for (int oc = 0; oc < 18; ++oc) acc[oc] = ob[oc];

    const float* xb = x + (size_t)b * CIN * HW;
    for (int c = 0; c < CIN; ++c) {
        const float* xc = xb + c * HW;
        float xv[9];
#pragma unroll
        for (int dh = 0; dh < 3; ++dh) {
            const int y = h + dh - 1;
            const bool vy = (unsigned)y < (unsigned)HDIM;
#pragma unroll
            for (int dw = 0; dw < 3; ++dw) {
                const int xw = w + dw - 1;
                const bool vx = (unsigned)xw < (unsigned)WDIM;
                float v = 0.0f;
                if (vy && vx) v = xc[y * WDIM + xw];
                xv[dh * 3 + dw] = v;
            }
        }
#pragma unroll
        for (int oc = 0; oc < 18; ++oc) {
            const float* wp = ow + ((size_t)oc * CIN + c) * 9;  // uniform -> s_load
#pragma unroll
            for (int t = 0; t < 9; ++t)
                acc[oc] = fmaf(xv[t], wp[t], acc[oc]);
        }
    }

    // absolute sampling positions: p = base_grid + offset
    // channel layout: offset.reshape(B, KK, 2, H, W) -> ch = kk*2 + {0:dy,1:dx}
#pragma unroll
    for (int kk = 0; kk < KK; ++kk) {
        const int ki = kk / 3, kj = kk % 3;
        const float pyv = (float)(h - 1 + ki) + acc[2 * kk];
        const float pxv = (float)(w - 1 + kj) + acc[2 * kk + 1];
        py[((size_t)b * KK + kk) * HW + pixel] = pyv;
        px[((size_t)b * KK + kk) * HW + pixel] = pxv;
    }
}

// ---------------------------------------------------------------------------
// Kernel B: fused bilinear sampling + implicit GEMM.
// Block = one output row (b, h): 128 pixels x 64 out-channels.
// Loop over 9 taps: [params -> LDS] [gather/blend A_lds[c][pix]] [reg GEMM].
// Thread tile: 8 pixels x 4 oc (32 accumulators).
// ---------------------------------------------------------------------------
__global__ __launch_bounds__(256) void deform_main_kernel(
    const float* __restrict__ x,
    const float* __restrict__ weight,  // [64][64][3][3]
    const float* __restrict__ py,
    const float* __restrict__ px,
    float* __restrict__ out)
{
    __shared__ float  A_lds[CIN][WDIM];   // 32 KB  sampled activations
    __shared__ float  W_lds[CIN][COUT];   // 16 KB  weight slice for tap k
    __shared__ int4   idx_lds[WDIM];      //  2 KB  4 clamped corner indices
    __shared__ float4 wt_lds[WDIM];       //  2 KB  4 bilinear weights (valid-folded)

    const int tid = threadIdx.x;
    const int b = blockIdx.x >> 7;
    const int h = blockIdx.x & 127;

    const int tx = tid & 15;   // oc group: oc = tx*4 .. tx*4+3
    const int ty = tid >> 4;   // pix group: pix = ty*8 .. ty*8+7

    float acc[8][4];
#pragma unroll
    for (int i = 0; i < 8; ++i)
#pragma unroll
        for (int j = 0; j < 4; ++j) acc[i][j] = 0.0f;

    const float* xb = x + (size_t)b * CIN * HW;
    const int pix_s = tid & 127;        // sampling-phase pixel
    const int c_base = (tid >> 7) * 32; // sampling-phase channel half

    for (int k = 0; k < KK; ++k) {
        __syncthreads();  // protect A_lds/W_lds from previous iteration readers

        // ---- phase 1: per-pixel sampling params (128 threads) + W slice stage
        if (tid < WDIM) {
            const int pix = tid;
            const float pyv = py[((size_t)b * KK + k) * HW + h * WDIM + pix];
            const float pxv = px[((size_t)b * KK + k) * HW + h * WDIM + pix];
            const float y0f = floorf(pyv);
            const float x0f = floorf(pxv);
            const float fy = pyv - y0f;
            const float fx = pxv - x0f;
            const int y0 = (int)y0f, x0 = (int)x0f;
            const int y1 = y0 + 1,  x1 = x0 + 1;
            const bool vy0 = (unsigned)y0 < (unsigned)HDIM;
            const bool vy1 = (unsigned)y1 < (unsigned)HDIM;
            const bool vx0 = (unsigned)x0 < (unsigned)WDIM;
            const bool vx1 = (unsigned)x1 < (unsigned)WDIM;
            const int cy0 = min(max(y0, 0), HDIM - 1);
            const int cy1 = min(max(y1, 0), HDIM - 1);
            const int cx0 = min(max(x0, 0), WDIM - 1);
            const int cx1 = min(max(x1, 0), WDIM - 1);
            idx_lds[pix] = make_int4(cy0 * WDIM + cx0, cy0 * WDIM + cx1,
                                     cy1 * WDIM + cx0, cy1 * WDIM + cx1);
            const float wy0 = 1.0f - fy, wy1 = fy;
            const float wx0 = 1.0f - fx, wx1 = fx;
            wt_lds[pix] = make_float4(wy0 * wx0 * (float)(vy0 && vx0),
                                      wy0 * wx1 * (float)(vy0 && vx1),
                                      wy1 * wx0 * (float)(vy1 && vx0),
                                      wy1 * wx1 * (float)(vy1 && vx1));
        }
        // W_lds[c][oc] = weight[oc][c][k]  (all 256 threads)
#pragma unroll
        for (int i = 0; i < 16; ++i) {
            const int e = tid + i * 256;  // 0..4095
            const int c = e >> 6, oc = e & 63;
            W_lds[c][oc] = weight[((size_t)oc * CIN + c) * KK + k];
        }
        __syncthreads();

        // ---- phase 2: gather + bilinear blend into A_lds[c][pix]
        {
            const int4   id = idx_lds[pix_s];
            const float4 wt = wt_lds[pix_s];
#pragma unroll 8
            for (int i = 0; i < 32; ++i) {
                const int c = c_base + i;
                const float* xc = xb + c * HW;
                const float v = wt.x * xc[id.x] + wt.y * xc[id.y]
                              + wt.z * xc[id.z] + wt.w * xc[id.w];
                A_lds[c][pix_s] = v;
            }
        }
        __syncthreads();

        // ---- phase 3: register-tiled GEMM over c
#pragma unroll 4
        for (int c = 0; c < CIN; ++c) {
            const float4 a0 = *(const float4*)&A_lds[c][ty * 8];
            const float4 a1 = *(const float4*)&A_lds[c][ty * 8 + 4];
            const float4 wv = *(const float4*)&W_lds[c][tx * 4];
            const float av[8] = {a0.x, a0.y, a0.z, a0.w, a1.x, a1.y, a1.z, a1.w};
            const float wj[4] = {wv.x, wv.y, wv.z, wv.w};
#pragma unroll
            for (int i = 0; i < 8; ++i)
#pragma unroll
                for (int j = 0; j < 4; ++j)
                    acc[i][j] = fmaf(av[i], wj[j], acc[i][j]);
        }
    }

    // ---- epilogue: coalesced float4 stores
    float* ob = out + (size_t)b * COUT * HW + (size_t)h * WDIM;
#pragma unroll
    for (int j = 0; j < 4; ++j) {
        const int oc = tx * 4 + j;
        const float4 v0 = make_float4(acc[0][j], acc[1][j], acc[2][j], acc[3][j]);
        const float4 v1 = make_float4(acc[4][j], acc[5][j], acc[6][j], acc[7][j]);
        *(float4*)(ob + (size_t)oc * HW + ty * 8)     = v0;
        *(float4*)(ob + (size_t)oc * HW + ty * 8 + 4) = v1;
    }
}

// ---------------------------------------------------------------------------
extern "C" void kernel_launch(void* const* d_in, const int* in_sizes, int n_in,
                              void* d_out, int out_size, void* d_ws, size_t ws_size,
                              hipStream_t stream)
{
    const float* x  = (const float*)d_in[0];
    const float* ow = (const float*)d_in[1];
    const float* ob = (const float*)d_in[2];
    const float* wt = (const float*)d_in[3];
    float* out = (float*)d_out;

    // workspace: py/px absolute sampling positions, [B][KK][HW] each (9.4 MB)
    float* py = (float*)d_ws;
    float* px = py + (size_t)BATCH * KK * HW;

    dim3 gridA(HW / 256, BATCH);
    offset_conv_kernel<<<gridA, 256, 0, stream>>>(x, ow, ob, py, px);

    deform_main_kernel<<<dim3(BATCH * HDIM), 256, 0, stream>>>(x, wt, py, px, out);
}